// Round 1
// baseline (2096.152 us; speedup 1.0000x reference)
//
#include <hip/hip_runtime.h>
#include <stdint.h>

typedef unsigned short u16;
typedef unsigned int   u32;

#define HW 65536   // 256*256

static __device__ __forceinline__ float bf2f(u16 h) {
    u32 u = ((u32)h) << 16;
    return __builtin_bit_cast(float, u);
}
static __device__ __forceinline__ u16 f2bf(float f) {
    u32 u = __builtin_bit_cast(u32, f);
    u += 0x7fffu + ((u >> 16) & 1u);   // RNE
    return (u16)(u >> 16);
}
static __device__ __forceinline__ void bf2x2(u32 u, float& a, float& b) {
    a = __builtin_bit_cast(float, u << 16);
    b = __builtin_bit_cast(float, u & 0xffff0000u);
}

// ---------------------------------------------------------------------------
// K0a: relative position bias MLP: (961,2) -> (961,6)
// ---------------------------------------------------------------------------
static __device__ __forceinline__ void lnrelu11(float* p, const float* __restrict__ w,
                                                const float* __restrict__ b) {
    float m = 0.f;
    #pragma unroll
    for (int k = 0; k < 11; k++) m += p[k];
    m *= (1.0f / 11.0f);
    float v = 0.f;
    #pragma unroll
    for (int k = 0; k < 11; k++) { float d = p[k] - m; v = fmaf(d, d, v); }
    v *= (1.0f / 11.0f);
    float r = 1.0f / sqrtf(v + 1e-5f);
    #pragma unroll
    for (int k = 0; k < 11; k++) {
        float t = (p[k] - m) * r * w[k] + b[k];
        p[k] = t > 0.f ? t : 0.f;
    }
}

__global__ __launch_bounds__(1024) void k_pos(
    const float* __restrict__ pw, const float* __restrict__ pb,
    const float* __restrict__ ln1w, const float* __restrict__ ln1b,
    const float* __restrict__ l1w, const float* __restrict__ l1b,
    const float* __restrict__ ln2w, const float* __restrict__ ln2b,
    const float* __restrict__ l2w, const float* __restrict__ l2b,
    const float* __restrict__ ln3w, const float* __restrict__ ln3b,
    const float* __restrict__ l3w, const float* __restrict__ l3b,
    float* __restrict__ pos)
{
    int i = threadIdx.x;
    if (i >= 961) return;
    float b0 = (float)(i / 31) - 15.0f;
    float b1 = (float)(i % 31) - 15.0f;
    float p[11], t[11];
    #pragma unroll
    for (int j = 0; j < 11; j++) p[j] = b0 * pw[j] + b1 * pw[11 + j] + pb[j];
    lnrelu11(p, ln1w, ln1b);
    #pragma unroll
    for (int j = 0; j < 11; j++) {
        float s = l1b[j];
        #pragma unroll
        for (int k = 0; k < 11; k++) s = fmaf(p[k], l1w[k * 11 + j], s);
        t[j] = s;
    }
    lnrelu11(t, ln2w, ln2b);
    #pragma unroll
    for (int j = 0; j < 11; j++) {
        float s = l2b[j];
        #pragma unroll
        for (int k = 0; k < 11; k++) s = fmaf(t[k], l2w[k * 11 + j], s);
        p[j] = s;
    }
    lnrelu11(p, ln3w, ln3b);
    #pragma unroll
    for (int h = 0; h < 6; h++) {
        float s = l3b[h];
        #pragma unroll
        for (int k = 0; k < 11; k++) s = fmaf(p[k], l3w[k * 6 + h], s);
        pos[i * 6 + h] = s;
    }
}

// ---------------------------------------------------------------------------
// K0b: rpb[h][l][m] = mean_r pos[idx(l, key(m,r))][h]   (6,256,64)
// ---------------------------------------------------------------------------
__global__ __launch_bounds__(256) void k_rpb(const float* __restrict__ pos,
                                             float* __restrict__ rpb)
{
    int g = blockIdx.x * 256 + threadIdx.x;
    if (g >= 6 * 256 * 64) return;
    int h = g >> 14;
    int l = (g >> 6) & 255;
    int m = g & 63;
    int yl = l >> 4, xl = l & 15;
    int my = m >> 3, mx = m & 7;
    float s = 0.f;
    #pragma unroll
    for (int ry = 0; ry < 2; ry++) {
        #pragma unroll
        for (int rx = 0; rx < 2; rx++) {
            int y2 = my * 2 + ry, x2 = mx * 2 + rx;
            int idx = (yl - y2 + 15) * 31 + (xl - x2 + 15);
            s += pos[idx * 6 + h];
        }
    }
    rpb[g] = 0.25f * s;
}

// ---------------------------------------------------------------------------
// K1: conv1x1 180->36 + lrelu.  x NCHW fp32 -> h1 planar bf16 [b][36][sp]
// ---------------------------------------------------------------------------
__global__ __launch_bounds__(256) void k_conv1(const float* __restrict__ x,
                                               const float* __restrict__ w,
                                               const float* __restrict__ b,
                                               u16* __restrict__ h1)
{
    int pix = blockIdx.x * 256 + threadIdx.x;
    int bb = pix >> 16, sp = pix & 65535;
    float acc[36];
    #pragma unroll
    for (int j = 0; j < 36; j++) acc[j] = b[j];
    const float* xp = x + (size_t)bb * 180 * HW + sp;
    for (int c = 0; c < 180; c++) {
        float xv = xp[(size_t)c * HW];
        #pragma unroll
        for (int j = 0; j < 36; j++) acc[j] = fmaf(xv, w[c * 36 + j], acc[j]);
    }
    u16* hp = h1 + (size_t)bb * 36 * HW + sp;
    #pragma unroll
    for (int j = 0; j < 36; j++) {
        float v = acc[j];
        v = v >= 0.f ? v : 0.2f * v;
        hp[(size_t)j * HW] = f2bf(v);
    }
}

// ---------------------------------------------------------------------------
// K2: conv3x3 36->36 pad1 + lrelu.  h1 planar bf16 -> h2 planar bf16
// ---------------------------------------------------------------------------
__global__ __launch_bounds__(256) void k_conv3(const u16* __restrict__ h1,
                                               const float* __restrict__ w,
                                               const float* __restrict__ b,
                                               u16* __restrict__ h2)
{
    int tx = threadIdx.x, ty = threadIdx.y;
    int x0 = blockIdx.x * 16 + tx;
    int y0 = blockIdx.y * 16 + ty;
    int bb = blockIdx.z;
    float acc[36];
    #pragma unroll
    for (int j = 0; j < 36; j++) acc[j] = b[j];
    const u16* base = h1 + (size_t)bb * 36 * HW;
    for (int ky = 0; ky < 3; ky++) {
        int yy = y0 + ky - 1;
        if (yy < 0 || yy >= 256) continue;
        for (int kx = 0; kx < 3; kx++) {
            int xx = x0 + kx - 1;
            if (xx < 0 || xx >= 256) continue;
            const u16* ip = base + yy * 256 + xx;
            const float* wp = w + ((ky * 3 + kx) * 36) * 36;
            for (int c = 0; c < 36; c++) {
                float v = bf2f(ip[(size_t)c * HW]);
                #pragma unroll
                for (int j = 0; j < 36; j++) acc[j] = fmaf(v, wp[c * 36 + j], acc[j]);
            }
        }
    }
    u16* op = h2 + (size_t)bb * 36 * HW + y0 * 256 + x0;
    #pragma unroll
    for (int j = 0; j < 36; j++) {
        float v = acc[j];
        v = v >= 0.f ? v : 0.2f * v;
        op[(size_t)j * HW] = f2bf(v);
    }
}

// ---------------------------------------------------------------------------
// K3: qv = (conv1x1 36->180 (h2) + b3) * (conv1x1 180->180 (x) + lb)
//     output NHWC bf16 [pix][180].  block (64,4): wave g owns 45 out-channels
// ---------------------------------------------------------------------------
__global__ __launch_bounds__(256) void k_gate(const u16* __restrict__ h2,
                                              const float* __restrict__ x,
                                              const float* __restrict__ w3,
                                              const float* __restrict__ b3,
                                              const float* __restrict__ lw,
                                              const float* __restrict__ lb,
                                              u16* __restrict__ qv)
{
    int pix = blockIdx.x * 64 + threadIdx.x;
    int g = __builtin_amdgcn_readfirstlane((int)threadIdx.y);
    int cb = g * 45;
    int bb = pix >> 16, sp = pix & 65535;
    float ah[45], al[45];
    #pragma unroll
    for (int j = 0; j < 45; j++) { ah[j] = b3[cb + j]; al[j] = lb[cb + j]; }
    const u16* hp = h2 + (size_t)bb * 36 * HW + sp;
    for (int c = 0; c < 36; c++) {
        float hv = bf2f(hp[(size_t)c * HW]);
        #pragma unroll
        for (int j = 0; j < 45; j++) ah[j] = fmaf(hv, w3[c * 180 + cb + j], ah[j]);
    }
    const float* xp = x + (size_t)bb * 180 * HW + sp;
    for (int c = 0; c < 180; c++) {
        float xv = xp[(size_t)c * HW];
        #pragma unroll
        for (int j = 0; j < 45; j++) al[j] = fmaf(xv, lw[c * 180 + cb + j], al[j]);
    }
    u16* qp = qv + (size_t)pix * 180 + cb;
    #pragma unroll
    for (int j = 0; j < 45; j++) qp[j] = f2bf(ah[j] * al[j]);
}

// ---------------------------------------------------------------------------
// K4a: spatial attention per 16x16 window.
//   vp[h][m][d] (LDS, d padded to 16) ; per-thread l: corr->xs streamed over m
//   writes y_pre channels [0,90)
// ---------------------------------------------------------------------------
__global__ __launch_bounds__(256) void k_spat(const u16* __restrict__ qv,
                                              const float* __restrict__ rpb,
                                              const float* __restrict__ slw,
                                              const float* __restrict__ slb,
                                              u16* __restrict__ yp)
{
    __shared__ __align__(16) float vp[6144];   // [6][64][16]
    int w = blockIdx.x;
    int bb = w >> 8, wy = (w >> 4) & 15, wx = w & 15;
    int t = threadIdx.x;
    float s0 = slw[0], s1 = slw[1], s2 = slw[2], s3 = slw[3], sb = slb[0];
    // phase 1: vp
    for (int it = 0; it < 24; it++) {
        int o = t + it * 256;
        int h = o >> 10, rem = o & 1023, m = rem >> 4, d = rem & 15;
        float s = 0.f;
        if (d < 15) {
            int my = m >> 3, mx = m & 7;
            int y2 = wy * 16 + my * 2, x2 = wx * 16 + mx * 2;
            const u16* vb = qv + (size_t)((bb * 256 + y2) * 256 + x2) * 180 + 90 + h * 15 + d;
            s = sb + s0 * bf2f(vb[0]) + s1 * bf2f(vb[180])
                   + s2 * bf2f(vb[180 * 256]) + s3 * bf2f(vb[180 * 257]);
        }
        vp[o] = s;
    }
    __syncthreads();
    // phase 2: per-thread l
    int l = t;
    int yl = wy * 16 + (l >> 4), xl = wx * 16 + (l & 15);
    size_t pixl = (size_t)(bb * 256 + yl) * 256 + xl;
    const u16* qp = qv + pixl * 180;
    u16* op = yp + pixl * 180;
    for (int h = 0; h < 6; h++) {
        float q[16];
        #pragma unroll
        for (int d = 0; d < 15; d++) q[d] = bf2f(qp[h * 15 + d]);
        q[15] = 0.f;
        float acc[16];
        #pragma unroll
        for (int d = 0; d < 16; d++) acc[d] = 0.f;
        const float* rp = rpb + ((h * 256 + l) << 6);
        const float4* vph = (const float4*)(vp + (h << 10));
        for (int m0 = 0; m0 < 64; m0 += 4) {
            float ra[4];
            *(float4*)ra = *(const float4*)(rp + m0);
            #pragma unroll
            for (int mm = 0; mm < 4; mm++) {
                int m = m0 + mm;
                float wv[16];
                ((float4*)wv)[0] = vph[m * 4 + 0];
                ((float4*)wv)[1] = vph[m * 4 + 1];
                ((float4*)wv)[2] = vph[m * 4 + 2];
                ((float4*)wv)[3] = vph[m * 4 + 3];
                float s = 0.f;
                #pragma unroll
                for (int d2 = 0; d2 < 16; d2++) s = fmaf(q[d2], wv[d2], s);
                s = s * (1.0f / 15.0f) + ra[mm];
                #pragma unroll
                for (int d2 = 0; d2 < 16; d2++) acc[d2] = fmaf(s, wv[d2], acc[d2]);
            }
        }
        #pragma unroll
        for (int d = 0; d < 15; d++) op[h * 15 + d] = f2bf(acc[d]);
    }
}

// ---------------------------------------------------------------------------
// K4b: channel self-correlation per window.
//   cmap[c][d] = sum_l q[l][c] v[l][d] / 256  (225 threads x 6x6 reg tiles)
//   xc[l][c] = sum_d cmap[c][d] v[l][d]   -> y_pre channels [90,180)
// ---------------------------------------------------------------------------
__global__ __launch_bounds__(256) void k_chan(const u16* __restrict__ qv,
                                              u16* __restrict__ yp)
{
    __shared__ __align__(16) float smem[8280];   // cmap [90][92] fp32 (33120 B); aliased chunk buf
    u16* chunkbuf = (u16*)smem;                  // [64][180] bf16 (23040 B)
    int w = blockIdx.x;
    int bb = w >> 8, wy = (w >> 4) & 15, wx = w & 15;
    int t = threadIdx.x;
    int rg = t / 15, cg = t % 15;
    int r0 = rg * 6, c0 = cg * 6;
    float acc[36];
    #pragma unroll
    for (int k = 0; k < 36; k++) acc[k] = 0.f;

    for (int chunk = 0; chunk < 4; chunk++) {
        __syncthreads();
        // stage 64 rows (= 4 window rows) as raw bf16, coalesced uint copies
        for (int seg = 0; seg < 4; seg++) {
            int iy = chunk * 4 + seg;
            const u32* gsrc = (const u32*)(qv + (size_t)((bb * 256 + wy * 16 + iy) * 256 + wx * 16) * 180);
            #pragma unroll
            for (int it = 0; it < 6; it++) {
                int k = t + it * 256;
                if (k < 1440) {
                    u32 u = gsrc[k];
                    int e = 2 * k;
                    int ix = e / 180, ch = e % 180;
                    *(u32*)(chunkbuf + (seg * 16 + ix) * 180 + ch) = u;
                }
            }
        }
        __syncthreads();
        if (t < 225) {
            for (int lo = 0; lo < 64; lo++) {
                const u16* row = chunkbuf + lo * 180;
                float qr[6], vr[6];
                #pragma unroll
                for (int i2 = 0; i2 < 3; i2++) {
                    bf2x2(*(const u32*)(row + r0 + i2 * 2), qr[i2 * 2], qr[i2 * 2 + 1]);
                    bf2x2(*(const u32*)(row + 90 + c0 + i2 * 2), vr[i2 * 2], vr[i2 * 2 + 1]);
                }
                #pragma unroll
                for (int i = 0; i < 6; i++)
                    #pragma unroll
                    for (int j = 0; j < 6; j++)
                        acc[i * 6 + j] = fmaf(qr[i], vr[j], acc[i * 6 + j]);
            }
        }
    }
    __syncthreads();
    if (t < 225) {
        #pragma unroll
        for (int i = 0; i < 6; i++)
            #pragma unroll
            for (int j = 0; j < 6; j++)
                smem[(r0 + i) * 92 + (c0 + j)] = acc[i * 6 + j] * (1.0f / 256.0f);
    }
    __syncthreads();
    // phase B: xc
    int l = t;
    int yl = wy * 16 + (l >> 4), xl = wx * 16 + (l & 15);
    size_t pixl = (size_t)(bb * 256 + yl) * 256 + xl;
    const u32* vsrc = (const u32*)(qv + pixl * 180 + 90);
    float vc[90];
    #pragma unroll
    for (int k = 0; k < 45; k++) bf2x2(vsrc[k], vc[2 * k], vc[2 * k + 1]);
    u16* op = yp + pixl * 180 + 90;
    for (int cg2 = 0; cg2 < 6; cg2++) {
        int cbB = cg2 * 15;
        float a[15];
        #pragma unroll
        for (int i = 0; i < 15; i++) a[i] = 0.f;
        for (int d0 = 0; d0 < 88; d0 += 4) {
            #pragma unroll
            for (int i = 0; i < 15; i++) {
                float4 wv = *(const float4*)(smem + (cbB + i) * 92 + d0);
                a[i] = fmaf(wv.x, vc[d0],
                       fmaf(wv.y, vc[d0 + 1],
                       fmaf(wv.z, vc[d0 + 2],
                       fmaf(wv.w, vc[d0 + 3], a[i]))));
            }
        }
        #pragma unroll
        for (int i = 0; i < 15; i++) {
            a[i] += smem[(cbB + i) * 92 + 88] * vc[88] + smem[(cbB + i) * 92 + 89] * vc[89];
            op[cbB + i] = f2bf(a[i]);
        }
    }
}

// ---------------------------------------------------------------------------
// K5: y = y_pre @ proj_w + proj_b ; RMSNorm ; + shortcut(x) ; write NCHW fp32
// ---------------------------------------------------------------------------
__global__ __launch_bounds__(256) void k_proj(const u16* __restrict__ yp,
                                              const float* __restrict__ x,
                                              const float* __restrict__ pw,
                                              const float* __restrict__ pb,
                                              const float* __restrict__ nw,
                                              float* __restrict__ out)
{
    __shared__ float tile[64 * 181];
    __shared__ float part[4][64];
    int lane = threadIdx.x;
    int g = __builtin_amdgcn_readfirstlane((int)threadIdx.y);
    int t = threadIdx.y * 64 + lane;
    int pix0 = blockIdx.x * 64;
    const u32* src = (const u32*)(yp + (size_t)pix0 * 180);
    #pragma unroll
    for (int it = 0; it < 23; it++) {
        int k = t + it * 256;
        if (k < 5760) {
            u32 u = src[k];
            int e = 2 * k, row = e / 180, ch = e % 180;
            float a, b2;
            bf2x2(u, a, b2);
            tile[row * 181 + ch] = a;
            tile[row * 181 + ch + 1] = b2;
        }
    }
    __syncthreads();
    int cb = g * 45;
    float acc[45];
    #pragma unroll
    for (int j = 0; j < 45; j++) acc[j] = 0.f;
    const float* trow = tile + lane * 181;
    for (int c = 0; c < 180; c++) {
        float yv = trow[c];
        #pragma unroll
        for (int j = 0; j < 45; j++) acc[j] = fmaf(yv, pw[c * 180 + cb + j], acc[j]);
    }
    float ss = 0.f;
    #pragma unroll
    for (int j = 0; j < 45; j++) {
        acc[j] += pb[cb + j];
        ss = fmaf(acc[j], acc[j], ss);
    }
    part[g][lane] = ss;
    __syncthreads();
    float tot = part[0][lane] + part[1][lane] + part[2][lane] + part[3][lane];
    float scale = 1.0f / sqrtf(tot * (1.0f / 180.0f) + 1.1920929e-7f);
    int pix = pix0 + lane;
    int bb = pix >> 16, sp = pix & 65535;
    const float* xs = x + (size_t)bb * 180 * HW + sp;
    float* os = out + (size_t)bb * 180 * HW + sp;
    #pragma unroll
    for (int j = 0; j < 45; j++) {
        int oc = cb + j;
        os[(size_t)oc * HW] = xs[(size_t)oc * HW] + acc[j] * scale * nw[oc];
    }
}

// ---------------------------------------------------------------------------
extern "C" void kernel_launch(void* const* d_in, const int* in_sizes, int n_in,
                              void* d_out, int out_size, void* d_ws, size_t ws_size,
                              hipStream_t stream)
{
    const float* x    = (const float*)d_in[0];
    const float* w1   = (const float*)d_in[1];
    const float* b1   = (const float*)d_in[2];
    const float* w2   = (const float*)d_in[3];
    const float* b2   = (const float*)d_in[4];
    const float* w3   = (const float*)d_in[5];
    const float* b3   = (const float*)d_in[6];
    const float* lw   = (const float*)d_in[7];
    const float* lb   = (const float*)d_in[8];
    const float* slw  = (const float*)d_in[9];
    const float* slb  = (const float*)d_in[10];
    const float* pw   = (const float*)d_in[11];
    const float* pb   = (const float*)d_in[12];
    const float* ln1w = (const float*)d_in[13];
    const float* ln1b = (const float*)d_in[14];
    const float* l1w  = (const float*)d_in[15];
    const float* l1b  = (const float*)d_in[16];
    const float* ln2w = (const float*)d_in[17];
    const float* ln2b = (const float*)d_in[18];
    const float* l2w  = (const float*)d_in[19];
    const float* l2b  = (const float*)d_in[20];
    const float* ln3w = (const float*)d_in[21];
    const float* ln3b = (const float*)d_in[22];
    const float* l3w  = (const float*)d_in[23];
    const float* l3b  = (const float*)d_in[24];
    const float* pjw  = (const float*)d_in[25];
    const float* pjb  = (const float*)d_in[26];
    const float* nw   = (const float*)d_in[27];
    float* out = (float*)d_out;

    char* ws = (char*)d_ws;
    float* pos = (float*)(ws + 0);            // 961*6 fp32
    float* rpb = (float*)(ws + 24576);        // 6*256*64 fp32 (393216 B)
    u16*  h1  = (u16*)(ws + 417792);          // 4*36*65536 bf16
    u16*  h2  = (u16*)(ws + 19292160);        // 4*36*65536 bf16
    u16*  qv  = (u16*)(ws + 38166528);        // 262144*180 bf16
    u16*  yp  = (u16*)(ws + 132538368);       // 262144*180 bf16
    // total ws use: ~227 MB

    k_pos<<<dim3(1), dim3(1024), 0, stream>>>(pw, pb, ln1w, ln1b, l1w, l1b,
                                              ln2w, ln2b, l2w, l2b, ln3w, ln3b,
                                              l3w, l3b, pos);
    k_rpb<<<dim3(384), dim3(256), 0, stream>>>(pos, rpb);
    k_conv1<<<dim3(1024), dim3(256), 0, stream>>>(x, w1, b1, h1);
    k_conv3<<<dim3(16, 16, 4), dim3(16, 16), 0, stream>>>(h1, w2, b2, h2);
    k_gate<<<dim3(4096), dim3(64, 4), 0, stream>>>(h2, x, w3, b3, lw, lb, qv);
    k_spat<<<dim3(1024), dim3(256), 0, stream>>>(qv, rpb, slw, slb, yp);
    k_chan<<<dim3(1024), dim3(256), 0, stream>>>(qv, yp);
    k_proj<<<dim3(4096), dim3(64, 4), 0, stream>>>(yp, x, pjw, pjb, nw, out);
}

// Round 2
// 1528.961 us; speedup vs baseline: 1.3710x; 1.3710x over previous
//
#include <hip/hip_runtime.h>
#include <stdint.h>

typedef unsigned short u16;
typedef unsigned int   u32;

#define HW 65536   // 256*256

typedef __bf16 bf16x8 __attribute__((ext_vector_type(8)));
typedef float  f32x4  __attribute__((ext_vector_type(4)));

static __device__ __forceinline__ float bf2f(u16 h) {
    u32 u = ((u32)h) << 16;
    return __builtin_bit_cast(float, u);
}
static __device__ __forceinline__ u16 f2bf(float f) {
    u32 u = __builtin_bit_cast(u32, f);
    u += 0x7fffu + ((u >> 16) & 1u);   // RNE
    return (u16)(u >> 16);
}
static __device__ __forceinline__ void bf2x2(u32 u, float& a, float& b) {
    a = __builtin_bit_cast(float, u << 16);
    b = __builtin_bit_cast(float, u & 0xffff0000u);
}
static __device__ __forceinline__ f32x4 mfma16(bf16x8 a, bf16x8 b, f32x4 c) {
    return __builtin_amdgcn_mfma_f32_16x16x32_bf16(a, b, c, 0, 0, 0);
}

// ---------------------------------------------------------------------------
// K0a: relative position bias MLP: (961,2) -> (961,6)
// ---------------------------------------------------------------------------
static __device__ __forceinline__ void lnrelu11(float* p, const float* __restrict__ w,
                                                const float* __restrict__ b) {
    float m = 0.f;
    #pragma unroll
    for (int k = 0; k < 11; k++) m += p[k];
    m *= (1.0f / 11.0f);
    float v = 0.f;
    #pragma unroll
    for (int k = 0; k < 11; k++) { float d = p[k] - m; v = fmaf(d, d, v); }
    v *= (1.0f / 11.0f);
    float r = 1.0f / sqrtf(v + 1e-5f);
    #pragma unroll
    for (int k = 0; k < 11; k++) {
        float t = (p[k] - m) * r * w[k] + b[k];
        p[k] = t > 0.f ? t : 0.f;
    }
}

__global__ __launch_bounds__(1024) void k_pos(
    const float* __restrict__ pw, const float* __restrict__ pb,
    const float* __restrict__ ln1w, const float* __restrict__ ln1b,
    const float* __restrict__ l1w, const float* __restrict__ l1b,
    const float* __restrict__ ln2w, const float* __restrict__ ln2b,
    const float* __restrict__ l2w, const float* __restrict__ l2b,
    const float* __restrict__ ln3w, const float* __restrict__ ln3b,
    const float* __restrict__ l3w, const float* __restrict__ l3b,
    float* __restrict__ pos)
{
    int i = threadIdx.x;
    if (i >= 961) return;
    float b0 = (float)(i / 31) - 15.0f;
    float b1 = (float)(i % 31) - 15.0f;
    float p[11], t[11];
    #pragma unroll
    for (int j = 0; j < 11; j++) p[j] = b0 * pw[j] + b1 * pw[11 + j] + pb[j];
    lnrelu11(p, ln1w, ln1b);
    #pragma unroll
    for (int j = 0; j < 11; j++) {
        float s = l1b[j];
        #pragma unroll
        for (int k = 0; k < 11; k++) s = fmaf(p[k], l1w[k * 11 + j], s);
        t[j] = s;
    }
    lnrelu11(t, ln2w, ln2b);
    #pragma unroll
    for (int j = 0; j < 11; j++) {
        float s = l2b[j];
        #pragma unroll
        for (int k = 0; k < 11; k++) s = fmaf(t[k], l2w[k * 11 + j], s);
        p[j] = s;
    }
    lnrelu11(p, ln3w, ln3b);
    #pragma unroll
    for (int h = 0; h < 6; h++) {
        float s = l3b[h];
        #pragma unroll
        for (int k = 0; k < 11; k++) s = fmaf(p[k], l3w[k * 6 + h], s);
        pos[i * 6 + h] = s;
    }
}

// ---------------------------------------------------------------------------
// K0b: rpb[h][l][m] = mean_r pos[idx(l, key(m,r))][h]   (6,256,64)
// ---------------------------------------------------------------------------
__global__ __launch_bounds__(256) void k_rpb(const float* __restrict__ pos,
                                             float* __restrict__ rpb)
{
    int g = blockIdx.x * 256 + threadIdx.x;
    if (g >= 6 * 256 * 64) return;
    int h = g >> 14;
    int l = (g >> 6) & 255;
    int m = g & 63;
    int yl = l >> 4, xl = l & 15;
    int my = m >> 3, mx = m & 7;
    float s = 0.f;
    #pragma unroll
    for (int ry = 0; ry < 2; ry++) {
        #pragma unroll
        for (int rx = 0; rx < 2; rx++) {
            int y2 = my * 2 + ry, x2 = mx * 2 + rx;
            int idx = (yl - y2 + 15) * 31 + (xl - x2 + 15);
            s += pos[idx * 6 + h];
        }
    }
    rpb[g] = 0.25f * s;
}

// ---------------------------------------------------------------------------
// K1: conv1x1 180->36 + lrelu.  x NCHW fp32 -> h1 planar bf16 [b][36][sp]
// ---------------------------------------------------------------------------
__global__ __launch_bounds__(256) void k_conv1(const float* __restrict__ x,
                                               const float* __restrict__ w,
                                               const float* __restrict__ b,
                                               u16* __restrict__ h1)
{
    int pix = blockIdx.x * 256 + threadIdx.x;
    int bb = pix >> 16, sp = pix & 65535;
    float acc[36];
    #pragma unroll
    for (int j = 0; j < 36; j++) acc[j] = b[j];
    const float* xp = x + (size_t)bb * 180 * HW + sp;
    for (int c = 0; c < 180; c++) {
        float xv = xp[(size_t)c * HW];
        #pragma unroll
        for (int j = 0; j < 36; j++) acc[j] = fmaf(xv, w[c * 36 + j], acc[j]);
    }
    u16* hp = h1 + (size_t)bb * 36 * HW + sp;
    #pragma unroll
    for (int j = 0; j < 36; j++) {
        float v = acc[j];
        v = v >= 0.f ? v : 0.2f * v;
        hp[(size_t)j * HW] = f2bf(v);
    }
}

// ---------------------------------------------------------------------------
// K2: conv3x3 36->36 pad1 + lrelu.  h1 planar bf16 -> h2 planar bf16
// ---------------------------------------------------------------------------
__global__ __launch_bounds__(256) void k_conv3(const u16* __restrict__ h1,
                                               const float* __restrict__ w,
                                               const float* __restrict__ b,
                                               u16* __restrict__ h2)
{
    int tx = threadIdx.x, ty = threadIdx.y;
    int x0 = blockIdx.x * 16 + tx;
    int y0 = blockIdx.y * 16 + ty;
    int bb = blockIdx.z;
    float acc[36];
    #pragma unroll
    for (int j = 0; j < 36; j++) acc[j] = b[j];
    const u16* base = h1 + (size_t)bb * 36 * HW;
    for (int ky = 0; ky < 3; ky++) {
        int yy = y0 + ky - 1;
        if (yy < 0 || yy >= 256) continue;
        for (int kx = 0; kx < 3; kx++) {
            int xx = x0 + kx - 1;
            if (xx < 0 || xx >= 256) continue;
            const u16* ip = base + yy * 256 + xx;
            const float* wp = w + ((ky * 3 + kx) * 36) * 36;
            for (int c = 0; c < 36; c++) {
                float v = bf2f(ip[(size_t)c * HW]);
                #pragma unroll
                for (int j = 0; j < 36; j++) acc[j] = fmaf(v, wp[c * 36 + j], acc[j]);
            }
        }
    }
    u16* op = h2 + (size_t)bb * 36 * HW + y0 * 256 + x0;
    #pragma unroll
    for (int j = 0; j < 36; j++) {
        float v = acc[j];
        v = v >= 0.f ? v : 0.2f * v;
        op[(size_t)j * HW] = f2bf(v);
    }
}

// ---------------------------------------------------------------------------
// K3: qv = (conv1x1 36->180 (h2) + b3) * (conv1x1 180->180 (x) + lb)
//     OUTPUT: per-window transposed qvT[w][ch][l]  (ch 0..180, l 0..256)
//     block = 4x16 pixel tile of one window => each channel store is one
//     full aligned 128B line of qvT.
// ---------------------------------------------------------------------------
__global__ __launch_bounds__(256) void k_gate(const u16* __restrict__ h2,
                                              const float* __restrict__ x,
                                              const float* __restrict__ w3,
                                              const float* __restrict__ b3,
                                              const float* __restrict__ lw,
                                              const float* __restrict__ lb,
                                              u16* __restrict__ qvT)
{
    int lane = threadIdx.x;
    int g = __builtin_amdgcn_readfirstlane((int)threadIdx.y);
    int cb = g * 45;
    int blk = blockIdx.x;
    int bb = blk >> 10;
    int r  = blk & 1023;
    int wx = r & 15;
    int yq = r >> 4;               // 0..63  (group of 4 image rows)
    int yl = lane >> 4, xl = lane & 15;
    int y  = yq * 4 + yl;
    int sp = y * 256 + wx * 16 + xl;
    int w  = bb * 256 + (yq >> 2) * 16 + wx;
    int l  = ((yq & 3) * 4 + yl) * 16 + xl;

    float ah[45], al[45];
    #pragma unroll
    for (int j = 0; j < 45; j++) { ah[j] = b3[cb + j]; al[j] = lb[cb + j]; }
    const u16* hp = h2 + (size_t)bb * 36 * HW + sp;
    for (int c = 0; c < 36; c++) {
        float hv = bf2f(hp[(size_t)c * HW]);
        #pragma unroll
        for (int j = 0; j < 45; j++) ah[j] = fmaf(hv, w3[c * 180 + cb + j], ah[j]);
    }
    const float* xp = x + (size_t)bb * 180 * HW + sp;
    for (int c = 0; c < 180; c++) {
        float xv = xp[(size_t)c * HW];
        #pragma unroll
        for (int j = 0; j < 45; j++) al[j] = fmaf(xv, lw[c * 180 + cb + j], al[j]);
    }
    u16* qp = qvT + (size_t)w * 180 * 256 + l;
    #pragma unroll
    for (int j = 0; j < 45; j++) qp[(size_t)(cb + j) * 256] = f2bf(ah[j] * al[j]);
}

// ---------------------------------------------------------------------------
// K4a: spatial attention per 16x16 window (reads qvT; writes yp slots 0..90)
// ---------------------------------------------------------------------------
__global__ __launch_bounds__(256) void k_spat(const u16* __restrict__ qvT,
                                              const float* __restrict__ rpb,
                                              const float* __restrict__ slw,
                                              const float* __restrict__ slb,
                                              u16* __restrict__ yp)
{
    __shared__ __align__(16) float vp[6144];   // [6][64][16]
    int w = blockIdx.x;
    int bb = w >> 8, wy = (w >> 4) & 15, wx = w & 15;
    int t = threadIdx.x;
    int lane = t & 63, wv = t >> 6;
    const u16* qw = qvT + (size_t)w * 180 * 256;
    float s0 = slw[0], s1 = slw[1], s2 = slw[2], s3 = slw[3], sb = slb[0];
    // zero pad d=15
    for (int o = t; o < 384; o += 256) vp[(o >> 6) * 1024 + (o & 63) * 16 + 15] = 0.f;
    // vp staging: wave handles one (h,d) row (p = h*15+d), lane = m
    for (int it = 0; it < 23; it++) {
        int p = wv + it * 4;
        if (p < 90) {
            int mm = lane;
            int l0 = (mm >> 3) * 32 + (mm & 7) * 2;
            const u16* rp2 = qw + (size_t)(90 + p) * 256;
            float s = sb + s0 * bf2f(rp2[l0]) + s1 * bf2f(rp2[l0 + 1])
                         + s2 * bf2f(rp2[l0 + 16]) + s3 * bf2f(rp2[l0 + 17]);
            vp[(p / 15) * 1024 + mm * 16 + (p % 15)] = s;
        }
    }
    __syncthreads();
    int l = t;
    size_t pixl = (size_t)((bb * 256 + wy * 16 + (l >> 4)) * 256 + wx * 16 + (l & 15));
    u16* op = yp + pixl * 192;
    for (int h = 0; h < 6; h++) {
        float q[16];
        #pragma unroll
        for (int d = 0; d < 15; d++) q[d] = bf2f(qw[(size_t)(h * 15 + d) * 256 + l]);
        q[15] = 0.f;
        float acc[16];
        #pragma unroll
        for (int d = 0; d < 16; d++) acc[d] = 0.f;
        const float* rp = rpb + ((h * 256 + l) << 6);
        const float4* vph = (const float4*)(vp + (h << 10));
        for (int m0 = 0; m0 < 64; m0 += 4) {
            float ra[4];
            *(float4*)ra = *(const float4*)(rp + m0);
            #pragma unroll
            for (int mm = 0; mm < 4; mm++) {
                int m = m0 + mm;
                float wvv[16];
                ((float4*)wvv)[0] = vph[m * 4 + 0];
                ((float4*)wvv)[1] = vph[m * 4 + 1];
                ((float4*)wvv)[2] = vph[m * 4 + 2];
                ((float4*)wvv)[3] = vph[m * 4 + 3];
                float s = 0.f;
                #pragma unroll
                for (int d2 = 0; d2 < 16; d2++) s = fmaf(q[d2], wvv[d2], s);
                s = s * (1.0f / 15.0f) + ra[mm];
                #pragma unroll
                for (int d2 = 0; d2 < 16; d2++) acc[d2] = fmaf(s, wvv[d2], acc[d2]);
            }
        }
        #pragma unroll
        for (int d = 0; d < 15; d++) op[h * 15 + d] = f2bf(acc[d]);
    }
}

// ---------------------------------------------------------------------------
// K4b: channel self-correlation per window — MFMA.
//   phase1: cmap[c][d] = (1/256) sum_l qc[l][c] vc[l][d]  via 16x16x32 bf16,
//           A/B fragments loaded straight from global qvT.  cmap -> LDS bf16.
//   phase2: xc[l][c] = sum_d vc[l][d] cmap[c][d]; A gathered from qvT,
//           B from LDS; xc staged in LDS, coalesced b128 copy to yp slots 96+.
// ---------------------------------------------------------------------------
__global__ __launch_bounds__(256) void k_chan(const u16* __restrict__ qvT,
                                              u16* __restrict__ yp)
{
    __shared__ __align__(16) u16 cm[96 * 104];     // cmap bf16, stride 104
    __shared__ __align__(16) u16 xcb[128 * 104];   // xc half, stride 104
    int w = blockIdx.x;
    int bb = w >> 8, wy = (w >> 4) & 15, wx = w & 15;
    int t = threadIdx.x;
    int lane = t & 63, wv = t >> 6;
    int m = lane & 15, quad = lane >> 4;
    const u16* qw = qvT + (size_t)w * 180 * 256;

    // ---- phase 1: cmap ----
    int ct0 = (wv & 1) * 3, dt0 = (wv >> 1) * 3;
    f32x4 acc[3][3];
    #pragma unroll
    for (int i = 0; i < 3; i++)
        #pragma unroll
        for (int j = 0; j < 3; j++) {
            f32x4 z = {0.f, 0.f, 0.f, 0.f};
            acc[i][j] = z;
        }
    #pragma unroll
    for (int ks = 0; ks < 8; ks++) {
        bf16x8 A[3], B[3];
        #pragma unroll
        for (int i = 0; i < 3; i++)
            A[i] = *(const bf16x8*)(qw + (size_t)((ct0 + i) * 16 + m) * 256 + ks * 32 + quad * 8);
        #pragma unroll
        for (int j = 0; j < 3; j++) {
            int d = (dt0 + j) * 16 + m;
            int dd = d > 89 ? 89 : d;
            B[j] = *(const bf16x8*)(qw + (size_t)(90 + dd) * 256 + ks * 32 + quad * 8);
        }
        #pragma unroll
        for (int i = 0; i < 3; i++)
            #pragma unroll
            for (int j = 0; j < 3; j++)
                acc[i][j] = mfma16(A[i], B[j], acc[i][j]);
    }
    #pragma unroll
    for (int i = 0; i < 3; i++)
        #pragma unroll
        for (int j = 0; j < 3; j++)
            #pragma unroll
            for (int r = 0; r < 4; r++)
                cm[((ct0 + i) * 16 + quad * 4 + r) * 104 + (dt0 + j) * 16 + m] =
                    f2bf(acc[i][j][r] * (1.0f / 256.0f));
    __syncthreads();
    if (t < 96) {   // zero cmap columns 90..95 (pad garbage)
        u32* z = (u32*)(cm + t * 104 + 90);
        z[0] = 0; z[1] = 0; z[2] = 0;
    }
    __syncthreads();

    // ---- phase 2: xc, in two 128-row halves ----
    int base_pix = (bb * 256 + wy * 16) * 256 + wx * 16;
    const __bf16* qwb = (const __bf16*)qw;
    for (int half = 0; half < 2; half++) {
        #pragma unroll
        for (int i = 0; i < 2; i++) {
            int ltl = wv * 2 + i;           // 0..7
            int lt = half * 8 + ltl;
            bf16x8 A[3];
            #pragma unroll
            for (int ks = 0; ks < 3; ks++) {
                const __bf16* colp = qwb + lt * 16 + m;
                #pragma unroll
                for (int j2 = 0; j2 < 8; j2++) {
                    int d = ks * 32 + quad * 8 + j2;
                    int dd = d > 89 ? 89 : d;
                    A[ks][j2] = colp[(size_t)(90 + dd) * 256];
                }
            }
            for (int ct = 0; ct < 6; ct++) {
                f32x4 c4 = {0.f, 0.f, 0.f, 0.f};
                #pragma unroll
                for (int ks = 0; ks < 3; ks++) {
                    bf16x8 B = *(const bf16x8*)(cm + (ct * 16 + m) * 104 + ks * 32 + quad * 8);
                    c4 = mfma16(A[ks], B, c4);
                }
                #pragma unroll
                for (int r = 0; r < 4; r++)
                    xcb[(ltl * 16 + quad * 4 + r) * 104 + ct * 16 + m] = f2bf(c4[r]);
            }
        }
        __syncthreads();
        #pragma unroll
        for (int it = 0; it < 6; it++) {
            int gg = t + it * 256;          // < 1536
            int lrow = gg / 12, seg = gg % 12;
            int l = half * 128 + lrow;
            int pix = base_pix + (l >> 4) * 256 + (l & 15);
            *(uint4*)(yp + (size_t)pix * 192 + 96 + seg * 8) =
                *(const uint4*)(xcb + lrow * 104 + seg * 8);
        }
        __syncthreads();
    }
}

// ---------------------------------------------------------------------------
// K5: y = y_pre @ proj_w + proj_b ; RMSNorm ; + shortcut(x) ; write NCHW fp32
//     yp layout: [pix][192], slots 0..90 = xs, 96..186 = xc.
// ---------------------------------------------------------------------------
__global__ __launch_bounds__(256) void k_proj(const u16* __restrict__ yp,
                                              const float* __restrict__ x,
                                              const float* __restrict__ pw,
                                              const float* __restrict__ pb,
                                              const float* __restrict__ nw,
                                              float* __restrict__ out)
{
    __shared__ float tile[64 * 181];
    __shared__ float part[4][64];
    int lane = threadIdx.x;
    int g = __builtin_amdgcn_readfirstlane((int)threadIdx.y);
    int t = threadIdx.y * 64 + lane;
    int pix0 = blockIdx.x * 64;
    const u32* src = (const u32*)(yp + (size_t)pix0 * 192);
    #pragma unroll
    for (int it = 0; it < 24; it++) {
        int k = t + it * 256;              // < 6144 = 64*96
        int row = k / 96, sp2 = k % 96;
        int col;
        if (sp2 < 45) col = 2 * sp2;
        else if (sp2 >= 48 && sp2 <= 92) col = 2 * sp2 - 6;
        else continue;
        u32 u = src[row * 96 + sp2];
        float a, b2;
        bf2x2(u, a, b2);
        tile[row * 181 + col] = a;
        tile[row * 181 + col + 1] = b2;
    }
    __syncthreads();
    int cb = g * 45;
    float acc[45];
    #pragma unroll
    for (int j = 0; j < 45; j++) acc[j] = 0.f;
    const float* trow = tile + lane * 181;
    for (int c = 0; c < 180; c++) {
        float yv = trow[c];
        #pragma unroll
        for (int j = 0; j < 45; j++) acc[j] = fmaf(yv, pw[c * 180 + cb + j], acc[j]);
    }
    float ss = 0.f;
    #pragma unroll
    for (int j = 0; j < 45; j++) {
        acc[j] += pb[cb + j];
        ss = fmaf(acc[j], acc[j], ss);
    }
    part[g][lane] = ss;
    __syncthreads();
    float tot = part[0][lane] + part[1][lane] + part[2][lane] + part[3][lane];
    float scale = 1.0f / sqrtf(tot * (1.0f / 180.0f) + 1.1920929e-7f);
    int pix = pix0 + lane;
    int bb = pix >> 16, sp = pix & 65535;
    const float* xs = x + (size_t)bb * 180 * HW + sp;
    float* os = out + (size_t)bb * 180 * HW + sp;
    #pragma unroll
    for (int j = 0; j < 45; j++) {
        int oc = cb + j;
        os[(size_t)oc * HW] = xs[(size_t)oc * HW] + acc[j] * scale * nw[oc];
    }
}

// ---------------------------------------------------------------------------
extern "C" void kernel_launch(void* const* d_in, const int* in_sizes, int n_in,
                              void* d_out, int out_size, void* d_ws, size_t ws_size,
                              hipStream_t stream)
{
    const float* x    = (const float*)d_in[0];
    const float* w1   = (const float*)d_in[1];
    const float* b1   = (const float*)d_in[2];
    const float* w2   = (const float*)d_in[3];
    const float* b2   = (const float*)d_in[4];
    const float* w3   = (const float*)d_in[5];
    const float* b3   = (const float*)d_in[6];
    const float* lw   = (const float*)d_in[7];
    const float* lb   = (const float*)d_in[8];
    const float* slw  = (const float*)d_in[9];
    const float* slb  = (const float*)d_in[10];
    const float* pw   = (const float*)d_in[11];
    const float* pb   = (const float*)d_in[12];
    const float* ln1w = (const float*)d_in[13];
    const float* ln1b = (const float*)d_in[14];
    const float* l1w  = (const float*)d_in[15];
    const float* l1b  = (const float*)d_in[16];
    const float* ln2w = (const float*)d_in[17];
    const float* ln2b = (const float*)d_in[18];
    const float* l2w  = (const float*)d_in[19];
    const float* l2b  = (const float*)d_in[20];
    const float* ln3w = (const float*)d_in[21];
    const float* ln3b = (const float*)d_in[22];
    const float* l3w  = (const float*)d_in[23];
    const float* l3b  = (const float*)d_in[24];
    const float* pjw  = (const float*)d_in[25];
    const float* pjb  = (const float*)d_in[26];
    const float* nw   = (const float*)d_in[27];
    float* out = (float*)d_out;

    char* ws = (char*)d_ws;
    // layout (time-disjoint overlap: qvT reuses dead h1 region)
    float* pos = (float*)(ws + 0);            // 23 KB
    float* rpb = (float*)(ws + 24576);        // 384 KB  -> end 417792
    u16*  h2  = (u16*)(ws + 417792);          // 18.87 MB -> end 19292160
    u16*  h1  = (u16*)(ws + 19292160);        // 18.87 MB -> end 38166528 (dead after conv3)
    u16*  qvT = (u16*)(ws + 19292160);        // 94.37 MB -> end 113664000 (written in k_gate)
    u16*  yp  = (u16*)(ws + 113664000);       // 100.66 MB -> end 214327296
    // total ws use: ~214.3 MB

    k_pos<<<dim3(1), dim3(1024), 0, stream>>>(pw, pb, ln1w, ln1b, l1w, l1b,
                                              ln2w, ln2b, l2w, l2b, ln3w, ln3b,
                                              l3w, l3b, pos);
    k_rpb<<<dim3(384), dim3(256), 0, stream>>>(pos, rpb);
    k_conv1<<<dim3(1024), dim3(256), 0, stream>>>(x, w1, b1, h1);
    k_conv3<<<dim3(16, 16, 4), dim3(16, 16), 0, stream>>>(h1, w2, b2, h2);
    k_gate<<<dim3(4096), dim3(64, 4), 0, stream>>>(h2, x, w3, b3, lw, lb, qvT);
    k_spat<<<dim3(1024), dim3(256), 0, stream>>>(qvT, rpb, slw, slb, yp);
    k_chan<<<dim3(1024), dim3(256), 0, stream>>>(qvT, yp);
    k_proj<<<dim3(4096), dim3(64, 4), 0, stream>>>(yp, x, pjw, pjb, nw, out);
}